// Round 4
// baseline (168.535 us; speedup 1.0000x reference)
//
#include <hip/hip_runtime.h>

// GaussianRecuModel: B=512 batches, T=8192-step affine recurrence on 2-state x.
//   x_{t+1} = Mt x_t + bt,  Mt = I + dt*A - dt*(xic_t C),  bt = xic_t dy_t
//   out_t   = dt * C x_t   (state BEFORE update)
//
// R4: wave-coalesced float4 global access; XOR-swizzled per-wave LDS slice
//     transposes coalesced order <-> 8-contiguous-steps-per-thread order.
// R5/R6: 2 KiB/wave slices (32 KiB/block). Falsified theory: halving LDS did
//     NOT raise occupancy (still ~1 block/CU, 35%) -> cross-block overlap is
//     unobtainable for 1024-thread blocks.
// R7: overlap moved INSIDE the block. grid 512 -> 256; each block processes
//     TWO batches. Batch-1 xic loads issue at the top (+32 VGPR), so batch-1
//     memory latency/BW hides under batch-0 compute+scan+replay. Batch-1 dy
//     loads issue after batch-0's second barrier (past the vmcnt(0) drain
//     point, keeping them off the register-pressure peak). Peak live regs
//     ~108 < 128, so __launch_bounds__(1024,4) holds without spill.

#define B_   512
#define T_   8192
#define LPT  8                  // steps per thread
#define NT   1024               // threads per block (16 waves)
#define NB   2                  // batches per block
static_assert(NT * LPT == T_, "one block covers one batch");

#define SLICE_F4 128            // 2 KiB per wave

struct Aff { float m00, m01, m10, m11, v0, v1; };

__device__ __forceinline__ Aff aff_compose(const Aff& L, const Aff& E) {
    Aff r;
    r.m00 = L.m00*E.m00 + L.m01*E.m10;
    r.m01 = L.m00*E.m01 + L.m01*E.m11;
    r.m10 = L.m10*E.m00 + L.m11*E.m10;
    r.m11 = L.m10*E.m01 + L.m11*E.m11;
    r.v0  = L.m00*E.v0  + L.m01*E.v1 + L.v0;
    r.v1  = L.m10*E.v0  + L.m11*E.v1 + L.v1;
    return r;
}

__device__ __forceinline__ Aff aff_identity() {
    Aff r; r.m00 = 1.f; r.m01 = 0.f; r.m10 = 0.f; r.m11 = 1.f; r.v0 = 0.f; r.v1 = 0.f;
    return r;
}

// STEP_MAP uses locals a[], d[] and the cd/i constants of the enclosing scope.
#define STEP_MAP(i, S)                                                  \
    {                                                                   \
        const float4 x4 = a[i];                                         \
        const float dyx = ((i)&1) ? d[(i)>>1].z : d[(i)>>1].x;          \
        const float dyy = ((i)&1) ? d[(i)>>1].w : d[(i)>>1].y;          \
        (S).m00 = i00 - (x4.x*cd00 + x4.y*cd10);                        \
        (S).m01 = i01 - (x4.x*cd01 + x4.y*cd11);                        \
        (S).m10 = i10 - (x4.z*cd00 + x4.w*cd10);                        \
        (S).m11 = i11 - (x4.z*cd01 + x4.w*cd11);                        \
        (S).v0  = x4.x*dyx + x4.y*dyy;                                  \
        (S).v1  = x4.z*dyx + x4.w*dyy;                                  \
    }

// Full per-batch pipeline: LDS transposes, local compose, wave scan, block
// scan via slice headers, replay, coalesced store. If PREFETCH_DY, issues the
// NEXT batch's dy loads right after the second barrier (past the vmcnt(0)
// drain, early enough to hide under this batch's replay + stores).
template<bool PREFETCH_DY>
__device__ __forceinline__ void process_batch(
    float4 (&t)[8], float4 (&u)[4],
    float4* __restrict__ slice, float4* __restrict__ lds4,
    const int lane, const int wave,
    const float cd00, const float cd01, const float cd10, const float cd11,
    const float i00, const float i01, const float i10, const float i11,
    float4* __restrict__ ow,
    const float4* __restrict__ dw_next, float4 (&u_next)[4])
{
    // ---- xic transpose: four owner-rounds through the 2 KiB slice ----
    // Round r covers f in [128r, 128r+128); owner o = f>>3, rel = o&15,
    // slot = lane&7, swizzled addr = rel*8 + (slot ^ (rel&7)).
    // Writes conflict-free; reads 2-way max (free). Same-wave DS ordering
    // makes cross-round slice reuse safe without barriers.
    float4 a[LPT];
    #pragma unroll
    for (int r = 0; r < 4; ++r) {
        #pragma unroll
        for (int jj = 0; jj < 2; ++jj) {
            int j = 2*r + jj;
            int f = j*64 + lane;
            int rel = (f >> 3) & 15;
            slice[rel*8 + ((lane & 7) ^ (rel & 7))] = t[j];
        }
        if ((lane >> 4) == r) {
            int rel = lane & 15;
            #pragma unroll
            for (int s = 0; s < LPT; ++s)
                a[s] = slice[rel*8 + (s ^ (rel & 7))];
        }
    }

    // ---- dy transpose: two owner-rounds. o = f>>2, rel = o&31, slot = f&3 ----
    float4 d[4];
    #pragma unroll
    for (int r = 0; r < 2; ++r) {
        #pragma unroll
        for (int jj = 0; jj < 2; ++jj) {
            int j = 2*r + jj;
            int f = j*64 + lane;
            int rel = (f >> 2) & 31;
            slice[rel*4 + ((lane & 3) ^ (rel & 3))] = u[j];
        }
        if ((lane >> 5) == r) {
            int rel = lane & 31;
            #pragma unroll
            for (int s = 0; s < 4; ++s)
                d[s] = slice[rel*4 + (s ^ (rel & 3))];
        }
    }

    // ---- thread-local compose: P = T7 o ... o T0 ----
    Aff P;
    STEP_MAP(0, P);
    #pragma unroll
    for (int i = 1; i < LPT; ++i) { Aff s; STEP_MAP(i, s); P = aff_compose(s, P); }

    // ---- wave Kogge-Stone inclusive scan (64 lanes) ----
    Aff S = P;
    #pragma unroll
    for (int sh = 1; sh < 64; sh <<= 1) {
        Aff q;
        q.m00 = __shfl_up(S.m00, sh); q.m01 = __shfl_up(S.m01, sh);
        q.m10 = __shfl_up(S.m10, sh); q.m11 = __shfl_up(S.m11, sh);
        q.v0  = __shfl_up(S.v0,  sh); q.v1  = __shfl_up(S.v1,  sh);
        if (lane >= sh) S = aff_compose(S, q);
    }

    // ---- wave totals -> own slice header (slice free: a,d in regs) ----
    if (lane == 63) {
        float* h = (float*)slice;
        h[0] = S.m00; h[1] = S.m01; h[2] = S.m10; h[3] = S.m11;
        h[4] = S.v0;  h[5] = S.v1;
    }
    __syncthreads();

    // ---- wave-exclusive prefix (serial over earlier waves' headers) ----
    Aff Ew = aff_identity();
    for (int w = 0; w < wave; ++w) {
        const float* h = (const float*)(lds4 + w * SLICE_F4);
        Aff t2;
        t2.m00 = h[0]; t2.m01 = h[1]; t2.m10 = h[2]; t2.m11 = h[3];
        t2.v0  = h[4]; t2.v1  = h[5];
        Ew = aff_compose(t2, Ew);
    }
    __syncthreads();   // headers consumed; slices reusable for out staging

    // ---- prefetch next batch's dy (post-drain point; hides under replay) ----
    if constexpr (PREFETCH_DY) {
        #pragma unroll
        for (int j = 0; j < 4; ++j) u_next[j] = dw_next[j*64 + lane];
    }

    // ---- lane-exclusive prefix within wave ----
    Aff El;
    El.m00 = __shfl_up(S.m00, 1); El.m01 = __shfl_up(S.m01, 1);
    El.m10 = __shfl_up(S.m10, 1); El.m11 = __shfl_up(S.m11, 1);
    El.v0  = __shfl_up(S.v0,  1); El.v1  = __shfl_up(S.v1,  1);
    if (lane == 0) El = aff_identity();

    Aff E = aff_compose(El, Ew);
    float x0 = E.m00 + E.v0;
    float x1 = E.m10 + E.v1;

    // ---- replay from registers ----
    float4 o4[4];
    #pragma unroll
    for (int i = 0; i < LPT; ++i) {
        float oxx = cd00*x0 + cd01*x1;
        float oyy = cd10*x0 + cd11*x1;
        if (i & 1) { o4[i>>1].z = oxx; o4[i>>1].w = oyy; }
        else       { o4[i>>1].x = oxx; o4[i>>1].y = oyy; }
        Aff s; STEP_MAP(i, s);
        float nx0 = s.m00*x0 + s.m01*x1 + s.v0;
        float nx1 = s.m10*x0 + s.m11*x1 + s.v1;
        x0 = nx0; x1 = nx1;
    }

    // ---- out transpose: own-order -> coalesced stores, two rounds ----
    #pragma unroll
    for (int r = 0; r < 2; ++r) {
        if ((lane >> 5) == r) {
            int rel = lane & 31;
            #pragma unroll
            for (int s = 0; s < 4; ++s)
                slice[rel*4 + (s ^ (rel & 3))] = o4[s];
        }
        #pragma unroll
        for (int jj = 0; jj < 2; ++jj) {
            int j = 2*r + jj;
            int f = j*64 + lane;
            int rel = (f >> 2) & 31;
            ow[f] = slice[rel*4 + ((lane & 3) ^ (rel & 3))];
        }
    }
}

__global__ __launch_bounds__(NT, 4) void grm_fused(
    const float* __restrict__ xic, const float* __restrict__ dy,
    const float* __restrict__ Aptr, const float* __restrict__ Cptr,
    float4* __restrict__ out4)
{
    // 16 waves x 128 float4 (2 KiB) = 32 KiB. Each wave uses ONLY its slice
    // except the header exchange (barrier-guarded). Slice is reused for both
    // batches (same-wave DS ordering + per-batch barriers make this safe).
    __shared__ float4 lds4[16 * SLICE_F4];

    const int tid  = threadIdx.x;
    const int lane = tid & 63;
    const int wave = tid >> 6;

    float4* slice = lds4 + wave * SLICE_F4;

    const float DT = 1e-3f;
    const float cd00 = Cptr[0]*DT, cd01 = Cptr[1]*DT;
    const float cd10 = Cptr[2]*DT, cd11 = Cptr[3]*DT;
    const float i00 = 1.0f + Aptr[0]*DT, i01 = Aptr[1]*DT;
    const float i10 = Aptr[2]*DT,        i11 = 1.0f + Aptr[3]*DT;

    // global bases in float4 units; wave covers 512 steps of each batch
    const int b0     = blockIdx.x * NB;
    const int wbase0 = b0 * T_ + wave * 512;                // batch 0 step idx
    const int wbase1 = wbase0 + T_;                          // batch 1 step idx
    const float4* xw0 = (const float4*)xic + wbase0;
    const float4* dw0 = (const float4*)dy  + (wbase0 >> 1);
    float4*       ow0 = out4 + (wbase0 >> 1);
    const float4* xw1 = (const float4*)xic + wbase1;
    const float4* dw1 = (const float4*)dy  + (wbase1 >> 1);
    float4*       ow1 = out4 + (wbase1 >> 1);

    // ---- issue batch-0 loads AND batch-1 xic loads, fully coalesced ----
    // Batch-1 xic (8 loads, 32 VGPR) rides out batch-0's entire compute
    // phase; its arrival is forced no later than batch-0's first barrier
    // (vmcnt(0) drain), exactly when we want it.
    float4 t0[8], u0[4], t1[8], u1[4];
    #pragma unroll
    for (int j = 0; j < 8; ++j) t0[j] = xw0[j*64 + lane];
    #pragma unroll
    for (int j = 0; j < 4; ++j) u0[j] = dw0[j*64 + lane];
    #pragma unroll
    for (int j = 0; j < 8; ++j) t1[j] = xw1[j*64 + lane];

    // ---- batch 0 (prefetches u1 at its post-barrier drain point) ----
    process_batch<true>(t0, u0, slice, lds4, lane, wave,
                        cd00, cd01, cd10, cd11, i00, i01, i10, i11,
                        ow0, dw1, u1);

    // ---- batch 1 ----
    process_batch<false>(t1, u1, slice, lds4, lane, wave,
                         cd00, cd01, cd10, cd11, i00, i01, i10, i11,
                         ow1, dw1, u1);
}

#undef STEP_MAP

extern "C" void kernel_launch(void* const* d_in, const int* in_sizes, int n_in,
                              void* d_out, int out_size, void* d_ws, size_t ws_size,
                              hipStream_t stream) {
    const float* xic  = (const float*)d_in[0];   // [B,T,2,2]
    const float* dy   = (const float*)d_in[1];   // [B,T,2]
    const float* Aptr = (const float*)d_in[2];   // [2,2]
    const float* Cptr = (const float*)d_in[3];   // [2,2]
    float4* out = (float4*)d_out;                // [B,T,2]

    grm_fused<<<B_ / NB, NT, 0, stream>>>(xic, dy, Aptr, Cptr, out);
}

// Round 5
// 166.129 us; speedup vs baseline: 1.0145x; 1.0145x over previous
//
#include <hip/hip_runtime.h>

// GaussianRecuModel: B=512 batches, T=8192-step affine recurrence on 2-state x.
//   x_{t+1} = Mt x_t + bt,  Mt = I + dt*A - dt*(xic_t C),  bt = xic_t dy_t
//   out_t   = dt * C x_t   (state BEFORE update)
//
// R4: wave-coalesced float4 global access; XOR-swizzled per-wave LDS slice
//     transposes coalesced order <-> 8-contiguous-steps-per-thread order.
// R5/R6: 2 KiB/wave slices (32 KiB/block). LDS is NOT the residency limiter
//     (still ~1 block/CU at 32 KiB) -> cross-block overlap unobtainable.
// R7: 2 batches/block software pipeline. Structure right (occupancy 35->42,
//     hbm up) but compiler targeted 64 VGPR and SPILLED: WRITE_SIZE 32->80MB,
//     FETCH 49->73MB, VALUBusy 21->10, dur 48->79us.
// R8: spill-free pipeline. (a) amdgpu_waves_per_eu(4,4) pins codegen at
//     4 waves/EU -> full 128-VGPR budget, removing the compiler's incentive
//     to shrink to 64. (b) prefetch issue points moved to live-range valleys:
//     t1 issues after batch-0's xic transpose (t0 dead), u1 issues after
//     batch-0's replay (a/d dead). Peak live ~110 < 128.

#define B_   512
#define T_   8192
#define LPT  8                  // steps per thread
#define NT   1024               // threads per block (16 waves)
#define NB   2                  // batches per block
static_assert(NT * LPT == T_, "one block covers one batch");

#define SLICE_F4 128            // 2 KiB per wave

struct Aff { float m00, m01, m10, m11, v0, v1; };

__device__ __forceinline__ Aff aff_compose(const Aff& L, const Aff& E) {
    Aff r;
    r.m00 = L.m00*E.m00 + L.m01*E.m10;
    r.m01 = L.m00*E.m01 + L.m01*E.m11;
    r.m10 = L.m10*E.m00 + L.m11*E.m10;
    r.m11 = L.m10*E.m01 + L.m11*E.m11;
    r.v0  = L.m00*E.v0  + L.m01*E.v1 + L.v0;
    r.v1  = L.m10*E.v0  + L.m11*E.v1 + L.v1;
    return r;
}

__device__ __forceinline__ Aff aff_identity() {
    Aff r; r.m00 = 1.f; r.m01 = 0.f; r.m10 = 0.f; r.m11 = 1.f; r.v0 = 0.f; r.v1 = 0.f;
    return r;
}

// STEP_MAP uses locals a[], d[] and the cd/i constants of the enclosing scope.
#define STEP_MAP(i, S)                                                  \
    {                                                                   \
        const float4 x4 = a[i];                                         \
        const float dyx = ((i)&1) ? d[(i)>>1].z : d[(i)>>1].x;          \
        const float dyy = ((i)&1) ? d[(i)>>1].w : d[(i)>>1].y;          \
        (S).m00 = i00 - (x4.x*cd00 + x4.y*cd10);                        \
        (S).m01 = i01 - (x4.x*cd01 + x4.y*cd11);                        \
        (S).m10 = i10 - (x4.z*cd00 + x4.w*cd10);                        \
        (S).m11 = i11 - (x4.z*cd01 + x4.w*cd11);                        \
        (S).v0  = x4.x*dyx + x4.y*dyy;                                  \
        (S).v1  = x4.z*dyx + x4.w*dyy;                                  \
    }

// Full per-batch pipeline. If PREFETCH: issues next batch's xic loads right
// after the xic transpose (this batch's t[] just died -> register valley),
// and next batch's dy loads right after replay (a[]/d[] just died).
template<bool PREFETCH>
__device__ __forceinline__ void process_batch(
    float4 (&t)[8], float4 (&u)[4],
    float4* __restrict__ slice, float4* __restrict__ lds4,
    const int lane, const int wave,
    const float cd00, const float cd01, const float cd10, const float cd11,
    const float i00, const float i01, const float i10, const float i11,
    float4* __restrict__ ow,
    const float4* __restrict__ xw_next, float4 (&t_next)[8],
    const float4* __restrict__ dw_next, float4 (&u_next)[4])
{
    // ---- xic transpose: four owner-rounds through the 2 KiB slice ----
    // Round r covers f in [128r, 128r+128); owner o = f>>3, rel = o&15,
    // slot = lane&7, swizzled addr = rel*8 + (slot ^ (rel&7)).
    // Writes conflict-free; reads 2-way max (free). Same-wave DS ordering
    // makes cross-round slice reuse safe without barriers.
    float4 a[LPT];
    #pragma unroll
    for (int r = 0; r < 4; ++r) {
        #pragma unroll
        for (int jj = 0; jj < 2; ++jj) {
            int j = 2*r + jj;
            int f = j*64 + lane;
            int rel = (f >> 3) & 15;
            slice[rel*8 + ((lane & 7) ^ (rel & 7))] = t[j];
        }
        if ((lane >> 4) == r) {
            int rel = lane & 15;
            #pragma unroll
            for (int s = 0; s < LPT; ++s)
                a[s] = slice[rel*8 + (s ^ (rel & 7))];
        }
    }

    // ---- prefetch next batch's xic: t[] is dead here (register valley).
    // These 8 loads overlap this batch's compose + scan; the first barrier's
    // vmcnt(0) drain bounds their arrival at end-of-scan, which is fine.
    if constexpr (PREFETCH) {
        #pragma unroll
        for (int j = 0; j < 8; ++j) t_next[j] = xw_next[j*64 + lane];
    }

    // ---- dy transpose: two owner-rounds. o = f>>2, rel = o&31, slot = f&3 ----
    float4 d[4];
    #pragma unroll
    for (int r = 0; r < 2; ++r) {
        #pragma unroll
        for (int jj = 0; jj < 2; ++jj) {
            int j = 2*r + jj;
            int f = j*64 + lane;
            int rel = (f >> 2) & 31;
            slice[rel*4 + ((lane & 3) ^ (rel & 3))] = u[j];
        }
        if ((lane >> 5) == r) {
            int rel = lane & 31;
            #pragma unroll
            for (int s = 0; s < 4; ++s)
                d[s] = slice[rel*4 + (s ^ (rel & 3))];
        }
    }

    // ---- thread-local compose: P = T7 o ... o T0 ----
    Aff P;
    STEP_MAP(0, P);
    #pragma unroll
    for (int i = 1; i < LPT; ++i) { Aff s; STEP_MAP(i, s); P = aff_compose(s, P); }

    // ---- wave Kogge-Stone inclusive scan (64 lanes) ----
    Aff S = P;
    #pragma unroll
    for (int sh = 1; sh < 64; sh <<= 1) {
        Aff q;
        q.m00 = __shfl_up(S.m00, sh); q.m01 = __shfl_up(S.m01, sh);
        q.m10 = __shfl_up(S.m10, sh); q.m11 = __shfl_up(S.m11, sh);
        q.v0  = __shfl_up(S.v0,  sh); q.v1  = __shfl_up(S.v1,  sh);
        if (lane >= sh) S = aff_compose(S, q);
    }

    // ---- wave totals -> own slice header (slice free: a,d in regs) ----
    if (lane == 63) {
        float* h = (float*)slice;
        h[0] = S.m00; h[1] = S.m01; h[2] = S.m10; h[3] = S.m11;
        h[4] = S.v0;  h[5] = S.v1;
    }
    __syncthreads();

    // ---- wave-exclusive prefix (serial over earlier waves' headers) ----
    Aff Ew = aff_identity();
    for (int w = 0; w < wave; ++w) {
        const float* h = (const float*)(lds4 + w * SLICE_F4);
        Aff t2;
        t2.m00 = h[0]; t2.m01 = h[1]; t2.m10 = h[2]; t2.m11 = h[3];
        t2.v0  = h[4]; t2.v1  = h[5];
        Ew = aff_compose(t2, Ew);
    }
    __syncthreads();   // headers consumed; slices reusable for out staging

    // ---- lane-exclusive prefix within wave ----
    Aff El;
    El.m00 = __shfl_up(S.m00, 1); El.m01 = __shfl_up(S.m01, 1);
    El.m10 = __shfl_up(S.m10, 1); El.m11 = __shfl_up(S.m11, 1);
    El.v0  = __shfl_up(S.v0,  1); El.v1  = __shfl_up(S.v1,  1);
    if (lane == 0) El = aff_identity();

    Aff E = aff_compose(El, Ew);
    float x0 = E.m00 + E.v0;
    float x1 = E.m10 + E.v1;

    // ---- replay from registers ----
    float4 o4[4];
    #pragma unroll
    for (int i = 0; i < LPT; ++i) {
        float oxx = cd00*x0 + cd01*x1;
        float oyy = cd10*x0 + cd11*x1;
        if (i & 1) { o4[i>>1].z = oxx; o4[i>>1].w = oyy; }
        else       { o4[i>>1].x = oxx; o4[i>>1].y = oyy; }
        Aff s; STEP_MAP(i, s);
        float nx0 = s.m00*x0 + s.m01*x1 + s.v0;
        float nx1 = s.m10*x0 + s.m11*x1 + s.v1;
        x0 = nx0; x1 = nx1;
    }

    // ---- prefetch next batch's dy: a[]/d[] dead (second valley). Overlaps
    // the out-transpose stores below and next batch's xic transpose.
    if constexpr (PREFETCH) {
        #pragma unroll
        for (int j = 0; j < 4; ++j) u_next[j] = dw_next[j*64 + lane];
    }

    // ---- out transpose: own-order -> coalesced stores, two rounds ----
    #pragma unroll
    for (int r = 0; r < 2; ++r) {
        if ((lane >> 5) == r) {
            int rel = lane & 31;
            #pragma unroll
            for (int s = 0; s < 4; ++s)
                slice[rel*4 + (s ^ (rel & 3))] = o4[s];
        }
        #pragma unroll
        for (int jj = 0; jj < 2; ++jj) {
            int j = 2*r + jj;
            int f = j*64 + lane;
            int rel = (f >> 2) & 31;
            ow[f] = slice[rel*4 + ((lane & 3) ^ (rel & 3))];
        }
    }
}

__global__ __launch_bounds__(NT)
__attribute__((amdgpu_waves_per_eu(4, 4)))
void grm_fused(
    const float* __restrict__ xic, const float* __restrict__ dy,
    const float* __restrict__ Aptr, const float* __restrict__ Cptr,
    float4* __restrict__ out4)
{
    // 16 waves x 128 float4 (2 KiB) = 32 KiB. Each wave uses ONLY its slice
    // except the header exchange (barrier-guarded). Slice is reused for both
    // batches (same-wave DS ordering + per-batch barriers make this safe).
    __shared__ float4 lds4[16 * SLICE_F4];

    const int tid  = threadIdx.x;
    const int lane = tid & 63;
    const int wave = tid >> 6;

    float4* slice = lds4 + wave * SLICE_F4;

    const float DT = 1e-3f;
    const float cd00 = Cptr[0]*DT, cd01 = Cptr[1]*DT;
    const float cd10 = Cptr[2]*DT, cd11 = Cptr[3]*DT;
    const float i00 = 1.0f + Aptr[0]*DT, i01 = Aptr[1]*DT;
    const float i10 = Aptr[2]*DT,        i11 = 1.0f + Aptr[3]*DT;

    // global bases in float4 units; wave covers 512 steps of each batch
    const int b0     = blockIdx.x * NB;
    const int wbase0 = b0 * T_ + wave * 512;                // batch 0 step idx
    const int wbase1 = wbase0 + T_;                          // batch 1 step idx
    const float4* xw0 = (const float4*)xic + wbase0;
    const float4* dw0 = (const float4*)dy  + (wbase0 >> 1);
    float4*       ow0 = out4 + (wbase0 >> 1);
    const float4* xw1 = (const float4*)xic + wbase1;
    const float4* dw1 = (const float4*)dy  + (wbase1 >> 1);
    float4*       ow1 = out4 + (wbase1 >> 1);

    // ---- batch-0 loads only; batch-1 loads issue at register valleys
    // inside process_batch<true> ----
    float4 t0[8], u0[4], t1[8], u1[4];
    #pragma unroll
    for (int j = 0; j < 8; ++j) t0[j] = xw0[j*64 + lane];
    #pragma unroll
    for (int j = 0; j < 4; ++j) u0[j] = dw0[j*64 + lane];

    // ---- batch 0 (prefetches t1 after its xic transpose, u1 after replay) ----
    process_batch<true>(t0, u0, slice, lds4, lane, wave,
                        cd00, cd01, cd10, cd11, i00, i01, i10, i11,
                        ow0, xw1, t1, dw1, u1);

    // ---- batch 1 ----
    process_batch<false>(t1, u1, slice, lds4, lane, wave,
                         cd00, cd01, cd10, cd11, i00, i01, i10, i11,
                         ow1, xw1, t1, dw1, u1);
}

#undef STEP_MAP

extern "C" void kernel_launch(void* const* d_in, const int* in_sizes, int n_in,
                              void* d_out, int out_size, void* d_ws, size_t ws_size,
                              hipStream_t stream) {
    const float* xic  = (const float*)d_in[0];   // [B,T,2,2]
    const float* dy   = (const float*)d_in[1];   // [B,T,2]
    const float* Aptr = (const float*)d_in[2];   // [2,2]
    const float* Cptr = (const float*)d_in[3];   // [2,2]
    float4* out = (float4*)d_out;                // [B,T,2]

    grm_fused<<<B_ / NB, NT, 0, stream>>>(xic, dy, Aptr, Cptr, out);
}

// Round 6
// 165.076 us; speedup vs baseline: 1.0210x; 1.0064x over previous
//
#include <hip/hip_runtime.h>

// GaussianRecuModel: B=512 batches, T=8192-step affine recurrence on 2-state x.
//   x_{t+1} = Mt x_t + bt,  Mt = I + dt*A - dt*(xic_t C),  bt = xic_t dy_t
//   out_t   = dt * C x_t   (state BEFORE update)
//
// R4: wave-coalesced float4 global access; XOR-swizzled per-wave LDS slice
//     transposes coalesced order <-> 8-contiguous-steps-per-thread order.
// R5/R6: 32 KiB/block. LDS is NOT the residency limiter (~1 block/CU even
//     at 32 KiB) -> cross-block overlap unobtainable for 1024-thr blocks.
// R7/R8: 2 batches/block pipeline with REGISTER prefetch: compiler refuses
//     >64 VGPR for 1024-thread blocks (both launch_bounds(NT,4) and
//     waves_per_eu(4,4)); spilled to scratch both times (WRITE_SIZE 32->48MB).
// R9: pipeline kept, prefetch moved to LDS. Batch-1 xic (7 KiB/wave) is
//     staged at kernel top via global_load_lds (ZERO dest registers) into a
//     112 KiB stage buffer in plain coalesced order (linear lane-contiguous
//     ds_read_b128 readback is the measured-optimal LDS pattern). Only the
//     1 KiB xic tail (+4 regs) and dy-1 (+16 regs) are register-prefetched,
//     at the post-replay valley where a[]/d[] just died. Per-batch register
//     flow is byte-identical to the 52-VGPR R6 kernel. LDS 144 KiB, grid 256
//     (one block per CU, single round, no tail).

#define B_   512
#define T_   8192
#define LPT  8                  // steps per thread
#define NT   1024               // threads per block (16 waves)
#define NB   2                  // batches per block
static_assert(NT * LPT == T_, "one block covers one batch");

#define SLICE_F4 128            // 2 KiB work slice per wave
#define STAGE_F4 448            // 7 KiB stage per wave (xic cols j=0..6)

struct Aff { float m00, m01, m10, m11, v0, v1; };

__device__ __forceinline__ Aff aff_compose(const Aff& L, const Aff& E) {
    Aff r;
    r.m00 = L.m00*E.m00 + L.m01*E.m10;
    r.m01 = L.m00*E.m01 + L.m01*E.m11;
    r.m10 = L.m10*E.m00 + L.m11*E.m10;
    r.m11 = L.m10*E.m01 + L.m11*E.m11;
    r.v0  = L.m00*E.v0  + L.m01*E.v1 + L.v0;
    r.v1  = L.m10*E.v0  + L.m11*E.v1 + L.v1;
    return r;
}

__device__ __forceinline__ Aff aff_identity() {
    Aff r; r.m00 = 1.f; r.m01 = 0.f; r.m10 = 0.f; r.m11 = 1.f; r.v0 = 0.f; r.v1 = 0.f;
    return r;
}

// Direct global->LDS copy, 16B per lane, no destination registers.
// LDS dest is wave-uniform base + lane*16 (linear); global src is per-lane.
__device__ __forceinline__ void glds16(const float4* g, float4* l) {
    __builtin_amdgcn_global_load_lds(
        (const __attribute__((address_space(1))) void*)g,
        (__attribute__((address_space(3))) void*)l,
        16, 0, 0);
}

// STEP_MAP uses locals a[], d[] and the cd/i constants of the enclosing scope.
#define STEP_MAP(i, S)                                                  \
    {                                                                   \
        const float4 x4 = a[i];                                         \
        const float dyx = ((i)&1) ? d[(i)>>1].z : d[(i)>>1].x;          \
        const float dyy = ((i)&1) ? d[(i)>>1].w : d[(i)>>1].y;          \
        (S).m00 = i00 - (x4.x*cd00 + x4.y*cd10);                        \
        (S).m01 = i01 - (x4.x*cd01 + x4.y*cd11);                        \
        (S).m10 = i10 - (x4.z*cd00 + x4.w*cd10);                        \
        (S).m11 = i11 - (x4.z*cd01 + x4.w*cd11);                        \
        (S).v0  = x4.x*dyx + x4.y*dyy;                                  \
        (S).v1  = x4.z*dyx + x4.w*dyy;                                  \
    }

// Full per-batch pipeline (register flow identical to the passing R6 kernel).
// If PREFETCH: at the post-replay register valley (a[]/d[] dead), issues the
// next batch's dy loads (16 regs) and xic tail load (4 regs).
template<bool PREFETCH>
__device__ __forceinline__ void process_batch(
    float4 (&t)[8], float4 (&u)[4],
    float4* __restrict__ slice, float4* __restrict__ ldsw,
    const int lane, const int wave,
    const float cd00, const float cd01, const float cd10, const float cd11,
    const float i00, const float i01, const float i10, const float i11,
    float4* __restrict__ ow,
    const float4* __restrict__ dw_next, float4 (&u_next)[4],
    const float4* __restrict__ xtail_next, float4& ttail_next)
{
    // ---- xic transpose: four owner-rounds through the 2 KiB work slice ----
    // Round r covers f in [128r, 128r+128); owner o = f>>3, rel = o&15,
    // slot = lane&7, swizzled addr = rel*8 + (slot ^ (rel&7)).
    // Writes conflict-free; reads 2-way max (free). Same-wave DS ordering
    // makes cross-round slice reuse safe without barriers.
    float4 a[LPT];
    #pragma unroll
    for (int r = 0; r < 4; ++r) {
        #pragma unroll
        for (int jj = 0; jj < 2; ++jj) {
            int j = 2*r + jj;
            int f = j*64 + lane;
            int rel = (f >> 3) & 15;
            slice[rel*8 + ((lane & 7) ^ (rel & 7))] = t[j];
        }
        if ((lane >> 4) == r) {
            int rel = lane & 15;
            #pragma unroll
            for (int s = 0; s < LPT; ++s)
                a[s] = slice[rel*8 + (s ^ (rel & 7))];
        }
    }

    // ---- dy transpose: two owner-rounds. o = f>>2, rel = o&31, slot = f&3 ----
    float4 d[4];
    #pragma unroll
    for (int r = 0; r < 2; ++r) {
        #pragma unroll
        for (int jj = 0; jj < 2; ++jj) {
            int j = 2*r + jj;
            int f = j*64 + lane;
            int rel = (f >> 2) & 31;
            slice[rel*4 + ((lane & 3) ^ (rel & 3))] = u[j];
        }
        if ((lane >> 5) == r) {
            int rel = lane & 31;
            #pragma unroll
            for (int s = 0; s < 4; ++s)
                d[s] = slice[rel*4 + (s ^ (rel & 3))];
        }
    }

    // ---- thread-local compose: P = T7 o ... o T0 ----
    Aff P;
    STEP_MAP(0, P);
    #pragma unroll
    for (int i = 1; i < LPT; ++i) { Aff s; STEP_MAP(i, s); P = aff_compose(s, P); }

    // ---- wave Kogge-Stone inclusive scan (64 lanes) ----
    Aff S = P;
    #pragma unroll
    for (int sh = 1; sh < 64; sh <<= 1) {
        Aff q;
        q.m00 = __shfl_up(S.m00, sh); q.m01 = __shfl_up(S.m01, sh);
        q.m10 = __shfl_up(S.m10, sh); q.m11 = __shfl_up(S.m11, sh);
        q.v0  = __shfl_up(S.v0,  sh); q.v1  = __shfl_up(S.v1,  sh);
        if (lane >= sh) S = aff_compose(S, q);
    }

    // ---- wave totals -> own slice header (slice free: a,d in regs) ----
    if (lane == 63) {
        float* h = (float*)slice;
        h[0] = S.m00; h[1] = S.m01; h[2] = S.m10; h[3] = S.m11;
        h[4] = S.v0;  h[5] = S.v1;
    }
    __syncthreads();   // also drains the top-of-kernel stage loads (vmcnt 0)

    // ---- wave-exclusive prefix (serial over earlier waves' headers) ----
    Aff Ew = aff_identity();
    for (int w = 0; w < wave; ++w) {
        const float* h = (const float*)(ldsw + w * SLICE_F4);
        Aff t2;
        t2.m00 = h[0]; t2.m01 = h[1]; t2.m10 = h[2]; t2.m11 = h[3];
        t2.v0  = h[4]; t2.v1  = h[5];
        Ew = aff_compose(t2, Ew);
    }
    __syncthreads();   // headers consumed; slices reusable for out staging

    // ---- lane-exclusive prefix within wave ----
    Aff El;
    El.m00 = __shfl_up(S.m00, 1); El.m01 = __shfl_up(S.m01, 1);
    El.m10 = __shfl_up(S.m10, 1); El.m11 = __shfl_up(S.m11, 1);
    El.v0  = __shfl_up(S.v0,  1); El.v1  = __shfl_up(S.v1,  1);
    if (lane == 0) El = aff_identity();

    Aff E = aff_compose(El, Ew);
    float x0 = E.m00 + E.v0;
    float x1 = E.m10 + E.v1;

    // ---- replay from registers ----
    float4 o4[4];
    #pragma unroll
    for (int i = 0; i < LPT; ++i) {
        float oxx = cd00*x0 + cd01*x1;
        float oyy = cd10*x0 + cd11*x1;
        if (i & 1) { o4[i>>1].z = oxx; o4[i>>1].w = oyy; }
        else       { o4[i>>1].x = oxx; o4[i>>1].y = oyy; }
        Aff s; STEP_MAP(i, s);
        float nx0 = s.m00*x0 + s.m01*x1 + s.v0;
        float nx1 = s.m10*x0 + s.m11*x1 + s.v1;
        x0 = nx0; x1 = nx1;
    }

    // ---- valley prefetch: a[]/d[] just died. dy-1 (16) + xic tail (4). ----
    // Covered by: out-transpose stores below + next batch's stage readback +
    // xic transpose (tail first used in round 3; dy first used after that).
    if constexpr (PREFETCH) {
        #pragma unroll
        for (int j = 0; j < 4; ++j) u_next[j] = dw_next[j*64 + lane];
        ttail_next = xtail_next[lane];
    }

    // ---- out transpose: own-order -> coalesced stores, two rounds ----
    #pragma unroll
    for (int r = 0; r < 2; ++r) {
        if ((lane >> 5) == r) {
            int rel = lane & 31;
            #pragma unroll
            for (int s = 0; s < 4; ++s)
                slice[rel*4 + (s ^ (rel & 3))] = o4[s];
        }
        #pragma unroll
        for (int jj = 0; jj < 2; ++jj) {
            int j = 2*r + jj;
            int f = j*64 + lane;
            int rel = (f >> 2) & 31;
            ow[f] = slice[rel*4 + ((lane & 3) ^ (rel & 3))];
        }
    }
}

__global__ __launch_bounds__(NT, 4) void grm_fused(
    const float* __restrict__ xic, const float* __restrict__ dy,
    const float* __restrict__ Aptr, const float* __restrict__ Cptr,
    float4* __restrict__ out4)
{
    // work: 16 waves x 2 KiB transposing slices (barrier-guarded headers).
    // stage: 16 waves x 7 KiB batch-1 xic landing zone (global_load_lds,
    //        linear coalesced order). Total 144 KiB -> 1 block/CU by design.
    __shared__ float4 work [16 * SLICE_F4];
    __shared__ float4 stage[16 * STAGE_F4];

    const int tid  = threadIdx.x;
    const int lane = tid & 63;
    const int wave = tid >> 6;

    float4* slice = work  + wave * SLICE_F4;
    float4* stw   = stage + wave * STAGE_F4;

    const float DT = 1e-3f;
    const float cd00 = Cptr[0]*DT, cd01 = Cptr[1]*DT;
    const float cd10 = Cptr[2]*DT, cd11 = Cptr[3]*DT;
    const float i00 = 1.0f + Aptr[0]*DT, i01 = Aptr[1]*DT;
    const float i10 = Aptr[2]*DT,        i11 = 1.0f + Aptr[3]*DT;

    // global bases in float4 units; wave covers 512 steps of each batch
    const int b0     = blockIdx.x * NB;
    const int wbase0 = b0 * T_ + wave * 512;                // batch 0 step idx
    const int wbase1 = wbase0 + T_;                          // batch 1 step idx
    const float4* xw0 = (const float4*)xic + wbase0;
    const float4* dw0 = (const float4*)dy  + (wbase0 >> 1);
    float4*       ow0 = out4 + (wbase0 >> 1);
    const float4* xw1 = (const float4*)xic + wbase1;
    const float4* dw1 = (const float4*)dy  + (wbase1 >> 1);
    float4*       ow1 = out4 + (wbase1 >> 1);

    // ---- batch-0 register loads, then batch-1 xic stage (zero regs).
    // Stage loads are younger than t0/u0 loads, so t0/u0 waits leave them
    // in flight; batch-0's first __syncthreads (vmcnt 0) bounds their
    // arrival right at the pipeline's natural sync point.
    float4 t0[8], u0[4], t1[8], u1[4];
    #pragma unroll
    for (int j = 0; j < 8; ++j) t0[j] = xw0[j*64 + lane];
    #pragma unroll
    for (int j = 0; j < 4; ++j) u0[j] = dw0[j*64 + lane];
    #pragma unroll
    for (int j = 0; j < 7; ++j) glds16(xw1 + j*64 + lane, stw + j*64);

    // ---- batch 0 (valley-prefetches u1 and t1's tail) ----
    process_batch<true>(t0, u0, slice, work, lane, wave,
                        cd00, cd01, cd10, cd11, i00, i01, i10, i11,
                        ow0, dw1, u1, xw1 + 7*64, t1[7]);

    // ---- batch-1 xic readback from stage (linear lane-contiguous b128) ----
    #pragma unroll
    for (int j = 0; j < 7; ++j) t1[j] = stw[j*64 + lane];

    // ---- batch 1 ----
    process_batch<false>(t1, u1, slice, work, lane, wave,
                         cd00, cd01, cd10, cd11, i00, i01, i10, i11,
                         ow1, dw1, u1, xw1, t1[7]);
}

#undef STEP_MAP

extern "C" void kernel_launch(void* const* d_in, const int* in_sizes, int n_in,
                              void* d_out, int out_size, void* d_ws, size_t ws_size,
                              hipStream_t stream) {
    const float* xic  = (const float*)d_in[0];   // [B,T,2,2]
    const float* dy   = (const float*)d_in[1];   // [B,T,2]
    const float* Aptr = (const float*)d_in[2];   // [2,2]
    const float* Cptr = (const float*)d_in[3];   // [2,2]
    float4* out = (float4*)d_out;                // [B,T,2]

    grm_fused<<<B_ / NB, NT, 0, stream>>>(xic, dy, Aptr, Cptr, out);
}